// Round 3
// baseline (331.855 us; speedup 1.0000x reference)
//
#include <hip/hip_runtime.h>
#include <stdint.h>

// ResNetV1 sparse conv block, MI355X (gfx950).
// out = relu( conv(relu(conv(x,W0)), W1) + x ),  conv[n,d] = sum_k sum_c x[idx[n,k],c] * W[k,c,d]
// N=150000, K=27, C=64.
// R11 = R9 skeleton (96 us/conv; saturates L2 fill port) + channel-split planar phases.
// HW model (calibrated on R9): conv is bound by the L2 miss-fill port, ~1 x 128B line
// fill /cycle/XCD = 8*128B*2.4GHz = 2.46 TB/s; R9 measured 238.5MB/96.0us = 2.48 TB/s.
// Only lever left: fewer fill bytes = higher L2 hit rate. feat is re-stored as TWO planar
// half-channel planes [2][N,32] (64B rows). Each block runs h=0 for all k, then h=1
// (grid ~fully co-resident => chip-wide working set halves to 9.6MB; each 128B line holds
// 2 same-plane rows => 2x touches/resident line). Same FLOPs/instr counts/LDS as R9.
// R10's pinned pipeline regressed (m141: sched_barrier pinning defeats scheduling) - reverted.

typedef __attribute__((ext_vector_type(8))) short short8;
typedef __attribute__((ext_vector_type(4))) float f32x4;

#define NV 150000
#define KOFF 27

static __device__ __forceinline__ ushort f2bf(float f) {
  union { float f; uint32_t u; } v; v.f = f;
  uint32_t u = v.u;
  return (ushort)((u + 0x7fffu + ((u >> 16) & 1u)) >> 16);
}

// Fused prep: x -> bf16 PLANAR [2][N,32] (4/thread), then pack W0, W1 into B-fragment order.
// Pack map: flat = (((t*4)+ct)*64 + l)*8 + jj, t = h*27+k
//   <- W[k][c = h*32 + (l>>4)*8 + jj][d = ct*16 + (l&15)]
__global__ void prep_kernel(const float* __restrict__ x,
                            const float* __restrict__ W0,
                            const float* __restrict__ W1,
                            ushort* __restrict__ xb,
                            ushort* __restrict__ wp0,
                            ushort* __restrict__ wp1,
                            int nc4, int wtot) {
  int i = blockIdx.x * 256 + threadIdx.x;
  if (i < nc4) {
    float4 v = ((const float4*)x)[i];
    ushort4 o;
    o.x = f2bf(v.x); o.y = f2bf(v.y); o.z = f2bf(v.z); o.w = f2bf(v.w);
    int f    = i << 2;                 // flat element, multiple of 4
    int nrow = f >> 6;
    int c    = f & 63;
    int h    = c >> 5;
    int off  = nrow * 32 + (c & 31);   // within plane, multiple of 4
    ((ushort4*)(xb + (size_t)h * NV * 32))[off >> 2] = o;
    return;
  }
  int o = i - nc4;
  const float* W = W0;
  ushort* wp = wp0;
  if (o >= wtot) { o -= wtot; W = W1; wp = wp1; }
  if (o >= wtot) return;
  int jj = o & 7;
  int l  = (o >> 3) & 63;
  int ct = (o >> 9) & 3;
  int t  = o >> 11;                    // substep 0..53
  int h  = t >= KOFF ? 1 : 0;
  int k  = t - h * KOFF;
  int c  = h * 32 + ((l >> 4) << 3) + jj;
  int d  = (ct << 4) + (l & 15);
  wp[o] = f2bf(W[(k * 64 + c) * 64 + d]);
}

// 4-wave block, 128 rows (each wave: 32 rows = 2 x 16-row MFMA tiles).
// 27 pair-iterations over 54 substeps t=(h,k); per pair: 4 gathers (64B half-rows),
// stage next pair's 8KB of packed W, 8 b-frags from LDS, 16 MFMAs, __syncthreads.
// MODE 0: relu(conv) -> bf16 PLANAR. MODE 1: relu(conv+resid) -> fp32 row-major.
template <int MODE>
__global__ __launch_bounds__(256, 5) void conv_kernel(
    const ushort* __restrict__ feat,   // PLANAR [2][N,32] bf16 bits
    const int*    __restrict__ nbr,    // [N,27]
    const ushort* __restrict__ wp,     // packed W, 54*2048 bf16 (4KB per substep)
    const float*  __restrict__ resid,  // [N,64] fp32 (MODE 1)
    ushort*       __restrict__ out_bf, // MODE 0, PLANAR [2][N,32]
    float*        __restrict__ out_f,  // MODE 1
    int n) {
  __shared__ __align__(16) int    sIdx[128 * KOFF];  // 128 rows x 27 offsets = 13824 B
  __shared__ __align__(16) ushort smB[2][4096];      // double-buffered pair (2 substeps), 8 KB each

  const int tid  = threadIdx.x;       // 0..255
  const int lane = tid & 63;
  const int wid  = tid >> 6;          // wave 0..3
  const int quad = lane >> 4;
  const int lo   = lane & 15;
  const int mw   = blockIdx.x * 128 + wid * 32;

  // ---- Prologue: stage pair 0 (substeps 0,1) into buf 0: 8 chunks of 1KB.
  #pragma unroll
  for (int u = 0; u < 2; ++u) {
    int c = wid * 2 + u;
    __builtin_amdgcn_global_load_lds(
        (const __attribute__((address_space(1))) void*)(wp + c * 512 + lane * 8),
        (__attribute__((address_space(3))) void*)(&smB[0][c * 512]), 16, 0, 0);
  }

  // ---- Stage block's idx rows: nbr[bid*128*27 .. +3456), contiguous, coalesced int4.
  {
    const int total = n * KOFF;
    const int g0    = blockIdx.x * (128 * KOFF);
    #pragma unroll
    for (int u = 0; u < 3; ++u) {
      int j  = tid + 256 * u;          // int4 index 0..767
      int ai = g0 + 4 * j;
      ai = ai + 4 <= total ? ai : (total - 4);   // clamp (tail block only)
      ((int4*)sIdx)[j] = *(const int4*)(nbr + ai);
    }
    if (tid < 96) {                    // int4 indices 768..863
      int j  = 768 + tid;
      int ai = g0 + 4 * j;
      ai = ai + 4 <= total ? ai : (total - 4);
      ((int4*)sIdx)[j] = *(const int4*)(nbr + ai);
    }
  }
  __syncthreads();   // full drain: stage(0) + idx loads complete

  int ioff[2];
  #pragma unroll
  for (int rt = 0; rt < 2; ++rt) ioff[rt] = (wid * 32 + rt * 16 + lo) * KOFF;

  f32x4 acc[2][4];
  #pragma unroll
  for (int rt = 0; rt < 2; ++rt)
    #pragma unroll
    for (int ct = 0; ct < 4; ++ct)
      acc[rt][ct] = (f32x4)0.0f;

  // idx for pair 0: substeps (h0,k0),(h0,k1).
  int gi[2][2];
  #pragma unroll
  for (int rt = 0; rt < 2; ++rt) {
    gi[0][rt] = sIdx[ioff[rt] + 0];
    gi[1][rt] = sIdx[ioff[rt] + 1];
  }

  #pragma unroll 1
  for (int p = 0; p < KOFF; ++p) {     // 27 pairs over 54 substeps
    const int buf = p & 1;
    const int j0 = 2 * p, j1 = 2 * p + 1;
    const int h0 = j0 >= KOFF ? 1 : 0;
    const int h1 = j1 >= KOFF ? 1 : 0;

    // Gathers first (random 64B half-rows; long latency, wave-TLP hides it).
    short8 a[2][2];                    // [sub][rt]
    {
      const ushort* pl0 = feat + (size_t)h0 * n * 32;
      const ushort* pl1 = feat + (size_t)h1 * n * 32;
      #pragma unroll
      for (int rt = 0; rt < 2; ++rt) {
        int g0r = gi[0][rt]; g0r = g0r < n ? g0r : 0;
        int g1r = gi[1][rt]; g1r = g1r < n ? g1r : 0;
        a[0][rt] = *(const short8*)(pl0 + g0r * 32 + quad * 8);
        a[1][rt] = *(const short8*)(pl1 + g1r * 32 + quad * 8);
      }
    }
    __builtin_amdgcn_sched_barrier(0);  // keep stage issue AFTER the gathers
    if (p + 1 < KOFF) {
      // Stage next pair's packed W (8 KB) into the other buffer.
      #pragma unroll
      for (int u = 0; u < 2; ++u) {
        int c = wid * 2 + u;
        __builtin_amdgcn_global_load_lds(
            (const __attribute__((address_space(1))) void*)(wp + (p + 1) * 4096 + c * 512 + lane * 8),
            (__attribute__((address_space(3))) void*)(&smB[buf ^ 1][c * 512]), 16, 0, 0);
      }
      // Next pair's idx from LDS (conflict-free: 27*lo mod 32 distinct; quad-broadcast).
      const int jn0 = 2 * (p + 1), jn1 = 2 * (p + 1) + 1;
      const int kk0 = jn0 - (jn0 >= KOFF ? KOFF : 0);
      const int kk1 = jn1 - (jn1 >= KOFF ? KOFF : 0);
      #pragma unroll
      for (int rt = 0; rt < 2; ++rt) {
        gi[0][rt] = sIdx[ioff[rt] + kk0];
        gi[1][rt] = sIdx[ioff[rt] + kk1];
      }
    }
    // B fragments from LDS + 16 MFMAs (8 per substep, K=32 = one half-channel block).
    #pragma unroll
    for (int sub = 0; sub < 2; ++sub) {
      const short8* bl = (const short8*)&smB[buf][sub * 2048];
      short8 b[4];
      #pragma unroll
      for (int ct = 0; ct < 4; ++ct) b[ct] = bl[ct * 64 + lane];
      #pragma unroll
      for (int rt = 0; rt < 2; ++rt)
        #pragma unroll
        for (int ct = 0; ct < 4; ++ct)
          acc[rt][ct] = __builtin_amdgcn_mfma_f32_16x16x32_bf16(a[sub][rt], b[ct], acc[rt][ct], 0, 0, 0);
    }
    // WAR guard for smB double-buffer (R9 structure: this measured fill-port saturation).
    __syncthreads();
  }

  // Epilogue: acc[rt][ct][j] -> row r = mw + rt*16 + quad*4 + j, col = ct*16 + lo.
  #pragma unroll
  for (int rt = 0; rt < 2; ++rt) {
    int rbase = mw + rt * 16 + quad * 4;
    #pragma unroll
    for (int ct = 0; ct < 4; ++ct) {
      int col = ct * 16 + lo;
      #pragma unroll
      for (int j = 0; j < 4; ++j) {
        int r = rbase + j;
        if (r < n) {
          float v = acc[rt][ct][j];
          if (MODE == 0) {
            v = v > 0.0f ? v : 0.0f;
            // planar write: plane = col>>5, within-plane col = col&31
            out_bf[(size_t)(col >> 5) * n * 32 + r * 32 + (col & 31)] = f2bf(v);
          } else {
            v += resid[r * 64 + col];
            v = v > 0.0f ? v : 0.0f;
            out_f[r * 64 + col] = v;
          }
        }
      }
    }
  }
}

extern "C" void kernel_launch(void* const* d_in, const int* in_sizes, int n_in,
                              void* d_out, int out_size, void* d_ws, size_t ws_size,
                              hipStream_t stream) {
  const float* x   = (const float*)d_in[0];
  const int*   nbr = (const int*)d_in[1];
  const float* W0  = (const float*)d_in[2];
  const float* W1  = (const float*)d_in[3];
  float* out = (float*)d_out;

  const int n    = NV;
  const int nc   = NV * 64;        // 9,600,000
  const int nc4  = nc / 4;         // 2,400,000
  const int wtot = KOFF * 4096;    // 110,592  (= 54 substeps * 2048)

  ushort* xb  = (ushort*)d_ws;     // planar [2][N,32]
  ushort* yb  = xb + nc;           // planar [2][N,32]
  ushort* wp0 = yb + nc;
  ushort* wp1 = wp0 + wtot;

  const int prep_units = nc4 + 2 * wtot;
  prep_kernel<<<(prep_units + 255) / 256, 256, 0, stream>>>(x, W0, W1, xb, wp0, wp1, nc4, wtot);

  const int grid = (n + 127) / 128;  // 1172 four-wave blocks (~fully co-resident)
  conv_kernel<0><<<grid, 256, 0, stream>>>(xb, nbr, wp0, nullptr, yb, nullptr, n);
  conv_kernel<1><<<grid, 256, 0, stream>>>(yb, nbr, wp1, x, nullptr, out, n);
}

// Round 4
// 273.214 us; speedup vs baseline: 1.2146x; 1.2146x over previous
//
#include <hip/hip_runtime.h>
#include <stdint.h>

// ResNetV1 sparse conv block, MI355X (gfx950).
// out = relu( conv(relu(conv(x,W0)), W1) + x ),  conv[n,d] = sum_k sum_c x[idx[n,k],c] * W[k,c,d]
// N=150000, K=27, C=64.
// R12 = R9 skeleton (96 us/conv) with 2-wave blocks x 64 rows/wave (was 4 x 32).
// Model history: R9 removed the B request stream (-13.5%); R11 (planar split) REFUTED the
// L2-fill-port model by sustaining 3.58 TB/s fetch (R9 sat at 2.48) -- the fabric has
// >=1.44x headroom. Remaining binder: latency x MLP. R9 drains vmcnt every k with only
// 4 gather instrs outstanding per wave; iter time ~= exposed miss latency. This round
// doubles per-wave outstanding gathers (8 instrs + 4 stage) per identical drain window:
// same grid (1172 blocks), same LDS (30208 B => 5 blocks/CU), same barrier structure,
// 32 MFMAs/iter. Little's law predicts ~2x touch service, capped by fabric headroom.
// Falsification: conv >= 90us & FETCH ~235MB => per-request queue wall => R9 ~ roofline.

typedef __attribute__((ext_vector_type(8))) short short8;
typedef __attribute__((ext_vector_type(4))) float f32x4;

#define NV 150000
#define KOFF 27

static __device__ __forceinline__ ushort f2bf(float f) {
  union { float f; uint32_t u; } v; v.f = f;
  uint32_t u = v.u;
  return (ushort)((u + 0x7fffu + ((u >> 16) & 1u)) >> 16);
}

// Fused prep: x -> bf16 (4/thread), then pack W0, W1 into B-fragment order.
// Pack map: flat = (((k*2+s)*4+ct)*64 + l)*8 + j <- W[k][c=s*32+(l>>4)*8+j][d=ct*16+(l&15)]
__global__ void prep_kernel(const float* __restrict__ x,
                            const float* __restrict__ W0,
                            const float* __restrict__ W1,
                            ushort* __restrict__ xb,
                            ushort* __restrict__ wp0,
                            ushort* __restrict__ wp1,
                            int nc4, int wtot) {
  int i = blockIdx.x * 256 + threadIdx.x;
  if (i < nc4) {
    float4 v = ((const float4*)x)[i];
    ushort4 o;
    o.x = f2bf(v.x); o.y = f2bf(v.y); o.z = f2bf(v.z); o.w = f2bf(v.w);
    ((ushort4*)xb)[i] = o;
    return;
  }
  int o = i - nc4;
  const float* W = W0;
  ushort* wp = wp0;
  if (o >= wtot) { o -= wtot; W = W1; wp = wp1; }
  if (o >= wtot) return;
  int j  = o & 7;
  int l  = (o >> 3) & 63;
  int ct = (o >> 9) & 3;
  int s  = (o >> 11) & 1;
  int k  = o >> 12;
  int c  = s * 32 + (l >> 4) * 8 + j;
  int d  = ct * 16 + (l & 15);
  wp[o] = f2bf(W[(k * 64 + c) * 64 + d]);
}

// 2-wave block, 128 rows (each wave: 64 rows = 4 x 16-row MFMA tiles).
// MODE 0: relu(conv) -> bf16. MODE 1: relu(conv+resid) -> fp32.
template <int MODE>
__global__ __launch_bounds__(128, 3) void conv_kernel(
    const ushort* __restrict__ feat,   // [N,64] bf16 bits
    const int*    __restrict__ nbr,    // [N,27]
    const ushort* __restrict__ wp,     // packed W, 27*4096 bf16
    const float*  __restrict__ resid,  // [N,64] fp32 (MODE 1)
    ushort*       __restrict__ out_bf, // MODE 0
    float*        __restrict__ out_f,  // MODE 1
    int n) {
  __shared__ __align__(16) int    sIdx[128 * KOFF];  // 128 rows x 27 offsets = 13824 B
  __shared__ __align__(16) ushort smB[2][4096];      // double-buffered W[k], 8 KB each

  const int tid  = threadIdx.x;       // 0..127
  const int lane = tid & 63;
  const int wid  = tid >> 6;          // wave 0..1
  const int quad = lane >> 4;
  const int lo   = lane & 15;
  const int mw   = blockIdx.x * 128 + wid * 64;

  // ---- Prologue: stage W[0] into buf 0 (8 chunks of 1KB; 4 per wave, wave-uniform base).
  #pragma unroll
  for (int u = 0; u < 4; ++u) {
    int c = wid * 4 + u;
    __builtin_amdgcn_global_load_lds(
        (const __attribute__((address_space(1))) void*)(wp + c * 512 + lane * 8),
        (__attribute__((address_space(3))) void*)(&smB[0][c * 512]), 16, 0, 0);
  }

  // ---- Stage block's idx rows: nbr[bid*128*27 .. +3456), contiguous, coalesced int4.
  {
    const int total = n * KOFF;
    const int g0    = blockIdx.x * (128 * KOFF);
    #pragma unroll
    for (int u = 0; u < 6; ++u) {
      int j  = tid + 128 * u;          // int4 index 0..767
      int ai = g0 + 4 * j;
      ai = ai + 4 <= total ? ai : (total - 4);   // clamp (tail block only)
      ((int4*)sIdx)[j] = *(const int4*)(nbr + ai);
    }
    if (tid < 96) {                    // int4 indices 768..863
      int j  = 768 + tid;
      int ai = g0 + 4 * j;
      ai = ai + 4 <= total ? ai : (total - 4);
      ((int4*)sIdx)[j] = *(const int4*)(nbr + ai);
    }
  }
  __syncthreads();  // drains idx staging + B[0] stage

  int ioff[4];
  #pragma unroll
  for (int rt = 0; rt < 4; ++rt) ioff[rt] = (wid * 64 + rt * 16 + lo) * KOFF;

  f32x4 acc[4][4];
  #pragma unroll
  for (int rt = 0; rt < 4; ++rt)
    #pragma unroll
    for (int ct = 0; ct < 4; ++ct)
      acc[rt][ct] = (f32x4)0.0f;

  int gi[4];
  #pragma unroll
  for (int rt = 0; rt < 4; ++rt) {
    int g = sIdx[ioff[rt]];
    gi[rt] = g < n ? g : 0;           // clamped-tail safety
  }

  #pragma unroll 1
  for (int k = 0; k < KOFF; ++k) {
    const int buf = k & 1;
    // A gathers FIRST: 8 random-row loads (2 per row-tile), deepest MLP in the window.
    short8 a[4][2];
    #pragma unroll
    for (int rt = 0; rt < 4; ++rt) {
      const ushort* rowp = feat + gi[rt] * 64 + quad * 8;
      a[rt][0] = *(const short8*)(rowp);
      a[rt][1] = *(const short8*)(rowp + 32);
    }
    __builtin_amdgcn_sched_barrier(0);  // keep stage issue AFTER the gathers
    // Stage next-k B into the other buffer; overlaps gather-wait + MFMA, drained at barrier.
    if (k + 1 < KOFF) {
      #pragma unroll
      for (int u = 0; u < 4; ++u) {
        int c = wid * 4 + u;
        __builtin_amdgcn_global_load_lds(
            (const __attribute__((address_space(1))) void*)(wp + (k + 1) * 4096 + c * 512 + lane * 8),
            (__attribute__((address_space(3))) void*)(&smB[buf ^ 1][c * 512]), 16, 0, 0);
      }
      // Next-k idx from LDS (conflict-free: 27*lo mod 32 distinct; quad-broadcast).
      #pragma unroll
      for (int rt = 0; rt < 4; ++rt) gi[rt] = sIdx[ioff[rt] + k + 1];
    }
    // B fragments from LDS (shared by both waves).
    const short8* bl = (const short8*)smB[buf];
    short8 b[8];
    #pragma unroll
    for (int t = 0; t < 8; ++t) b[t] = bl[t * 64 + lane];
    // 32 MFMAs.
    #pragma unroll
    for (int s = 0; s < 2; ++s)
      #pragma unroll
      for (int rt = 0; rt < 4; ++rt)
        #pragma unroll
        for (int ct = 0; ct < 4; ++ct)
          acc[rt][ct] = __builtin_amdgcn_mfma_f32_16x16x32_bf16(a[rt][s], b[s * 4 + ct], acc[rt][ct], 0, 0, 0);
    // WAR guard for smB double-buffer (R9 structure).
    __syncthreads();
  }

  // Epilogue: acc[rt][ct][j] -> out[mw + rt*16 + quad*4 + j][ct*16 + lo]
  #pragma unroll
  for (int rt = 0; rt < 4; ++rt) {
    int rbase = mw + rt * 16 + quad * 4;
    #pragma unroll
    for (int ct = 0; ct < 4; ++ct) {
      int col = ct * 16 + lo;
      #pragma unroll
      for (int j = 0; j < 4; ++j) {
        int r = rbase + j;
        if (r < n) {
          float v = acc[rt][ct][j];
          if (MODE == 0) {
            v = v > 0.0f ? v : 0.0f;
            out_bf[r * 64 + col] = f2bf(v);
          } else {
            v += resid[r * 64 + col];
            v = v > 0.0f ? v : 0.0f;
            out_f[r * 64 + col] = v;
          }
        }
      }
    }
  }
}

extern "C" void kernel_launch(void* const* d_in, const int* in_sizes, int n_in,
                              void* d_out, int out_size, void* d_ws, size_t ws_size,
                              hipStream_t stream) {
  const float* x   = (const float*)d_in[0];
  const int*   nbr = (const int*)d_in[1];
  const float* W0  = (const float*)d_in[2];
  const float* W1  = (const float*)d_in[3];
  float* out = (float*)d_out;

  const int n    = NV;
  const int nc   = NV * 64;        // 9,600,000
  const int nc4  = nc / 4;         // 2,400,000
  const int wtot = KOFF * 4096;    // 110,592

  ushort* xb  = (ushort*)d_ws;
  ushort* yb  = xb + nc;
  ushort* wp0 = yb + nc;
  ushort* wp1 = wp0 + wtot;

  const int prep_units = nc4 + 2 * wtot;
  prep_kernel<<<(prep_units + 255) / 256, 256, 0, stream>>>(x, W0, W1, xb, wp0, wp1, nc4, wtot);

  const int grid = (n + 127) / 128;  // 1172 two-wave blocks
  conv_kernel<0><<<grid, 128, 0, stream>>>(xb, nbr, wp0, nullptr, yb, nullptr, n);
  conv_kernel<1><<<grid, 128, 0, stream>>>(yb, nbr, wp1, x, nullptr, out, n);
}

// Round 5
// 264.054 us; speedup vs baseline: 1.2568x; 1.0347x over previous
//
#include <hip/hip_runtime.h>
#include <stdint.h>

// ResNetV1 sparse conv block, MI355X (gfx950).
// out = relu( conv(relu(conv(x,W0)), W1) + x ),  conv[n,d] = sum_k sum_c x[idx[n,k],c] * W[k,c,d]
// N=150000, K=27, C=64.
// R13 = R9 structure (best: 96 us/conv) + full-line LDS-repacked epilogue for conv1.
// Service-cap model (calibrated R9/R11/R12): T = a*sector_reqs + b*line_fills with
// a=0.0154 cy/req (cap ~65/cy chip), b=0.0577 cy/fill (cap ~17/cy). R9 saturates it
// (sum of fractions = 1.00); R10/R12 showed adding outstanding doesn't raise throughput
// (grid fully co-resident; service-capped). Irreducibles: 8.1M reqs = 518MB/64B (bf16
// mandated by accuracy), 1.84M fills = random 19.2MB vs 4MiB/XCD L2 (R11 refuted layout
// fixes). Last addressable term: conv1 FETCH==conv2 FETCH despite conv2's +38MB resid
// read => conv1 carries ~19-38MB write-allocate/RMW from scalar 2B bf16 stores (32B
// partial sectors). Fix: stage the 128x64 bf16 output tile in LDS (exactly 16KB = smB),
// store as coalesced full-line int4. If conv1 FETCH doesn't drop: R9 is the roofline.

typedef __attribute__((ext_vector_type(8))) short short8;
typedef __attribute__((ext_vector_type(4))) float f32x4;

#define NV 150000
#define KOFF 27

static __device__ __forceinline__ ushort f2bf(float f) {
  union { float f; uint32_t u; } v; v.f = f;
  uint32_t u = v.u;
  return (ushort)((u + 0x7fffu + ((u >> 16) & 1u)) >> 16);
}

// Fused prep: x -> bf16 (4/thread), then pack W0, W1 into B-fragment order.
// Pack map: flat = (((k*2+s)*4+ct)*64 + l)*8 + j <- W[k][c=s*32+(l>>4)*8+j][d=ct*16+(l&15)]
__global__ void prep_kernel(const float* __restrict__ x,
                            const float* __restrict__ W0,
                            const float* __restrict__ W1,
                            ushort* __restrict__ xb,
                            ushort* __restrict__ wp0,
                            ushort* __restrict__ wp1,
                            int nc4, int wtot) {
  int i = blockIdx.x * 256 + threadIdx.x;
  if (i < nc4) {
    float4 v = ((const float4*)x)[i];
    ushort4 o;
    o.x = f2bf(v.x); o.y = f2bf(v.y); o.z = f2bf(v.z); o.w = f2bf(v.w);
    ((ushort4*)xb)[i] = o;
    return;
  }
  int o = i - nc4;
  const float* W = W0;
  ushort* wp = wp0;
  if (o >= wtot) { o -= wtot; W = W1; wp = wp1; }
  if (o >= wtot) return;
  int j  = o & 7;
  int l  = (o >> 3) & 63;
  int ct = (o >> 9) & 3;
  int s  = (o >> 11) & 1;
  int k  = o >> 12;
  int c  = s * 32 + (l >> 4) * 8 + j;
  int d  = ct * 16 + (l & 15);
  wp[o] = f2bf(W[(k * 64 + c) * 64 + d]);
}

// 4-wave block, 128 rows (each wave: 32 rows = 2 x 16-row MFMA tiles).
// MODE 0: relu(conv) -> bf16 (LDS-repacked full-line stores). MODE 1: relu(conv+resid) -> fp32.
template <int MODE>
__global__ __launch_bounds__(256, 5) void conv_kernel(
    const ushort* __restrict__ feat,   // [N,64] bf16 bits
    const int*    __restrict__ nbr,    // [N,27]
    const ushort* __restrict__ wp,     // packed W, 27*4096 bf16
    const float*  __restrict__ resid,  // [N,64] fp32 (MODE 1)
    ushort*       __restrict__ out_bf, // MODE 0
    float*        __restrict__ out_f,  // MODE 1
    int n) {
  __shared__ __align__(16) int    sIdx[128 * KOFF];  // 128 rows x 27 offsets = 13824 B
  __shared__ __align__(16) ushort smB[2][4096];      // double-buffered W[k], 8 KB each
                                                     // (reused post-loop as 128x64 out tile)

  const int tid  = threadIdx.x;       // 0..255
  const int lane = tid & 63;
  const int wid  = tid >> 6;          // wave 0..3
  const int quad = lane >> 4;
  const int lo   = lane & 15;
  const int mw   = blockIdx.x * 128 + wid * 32;

  // ---- Prologue: stage W[0] into buf 0 (8 chunks of 1KB, wave-uniform LDS base).
  #pragma unroll
  for (int u = 0; u < 2; ++u) {
    int c = wid * 2 + u;
    __builtin_amdgcn_global_load_lds(
        (const __attribute__((address_space(1))) void*)(wp + c * 512 + lane * 8),
        (__attribute__((address_space(3))) void*)(&smB[0][c * 512]), 16, 0, 0);
  }

  // ---- Stage block's idx rows: nbr[bid*128*27 .. +3456), contiguous, coalesced int4.
  {
    const int total = n * KOFF;
    const int g0    = blockIdx.x * (128 * KOFF);
    #pragma unroll
    for (int u = 0; u < 3; ++u) {
      int j  = tid + 256 * u;          // int4 index 0..767
      int ai = g0 + 4 * j;
      ai = ai + 4 <= total ? ai : (total - 4);   // clamp (tail block only)
      ((int4*)sIdx)[j] = *(const int4*)(nbr + ai);
    }
    if (tid < 96) {                    // int4 indices 768..863
      int j  = 768 + tid;
      int ai = g0 + 4 * j;
      ai = ai + 4 <= total ? ai : (total - 4);
      ((int4*)sIdx)[j] = *(const int4*)(nbr + ai);
    }
  }
  __syncthreads();  // drains idx staging + B[0] stage

  int ioff[2];
  #pragma unroll
  for (int rt = 0; rt < 2; ++rt) ioff[rt] = (wid * 32 + rt * 16 + lo) * KOFF;

  f32x4 acc[2][4];
  #pragma unroll
  for (int rt = 0; rt < 2; ++rt)
    #pragma unroll
    for (int ct = 0; ct < 4; ++ct)
      acc[rt][ct] = (f32x4)0.0f;

  int gi[2];
  #pragma unroll
  for (int rt = 0; rt < 2; ++rt) {
    int g = sIdx[ioff[rt]];
    gi[rt] = g < n ? g : 0;           // clamped-tail safety
  }

  #pragma unroll 1
  for (int k = 0; k < KOFF; ++k) {
    const int buf = k & 1;
    // A gathers FIRST (random rows -> long latency; issue first).
    short8 a[2][2];
    #pragma unroll
    for (int rt = 0; rt < 2; ++rt) {
      const ushort* rowp = feat + gi[rt] * 64 + quad * 8;
      a[rt][0] = *(const short8*)(rowp);
      a[rt][1] = *(const short8*)(rowp + 32);
    }
    __builtin_amdgcn_sched_barrier(0);  // keep stage issue AFTER the gathers
    // Stage next-k B into the other buffer; overlaps gather-wait + MFMA, drained at barrier.
    if (k + 1 < KOFF) {
      #pragma unroll
      for (int u = 0; u < 2; ++u) {
        int c = wid * 2 + u;
        __builtin_amdgcn_global_load_lds(
            (const __attribute__((address_space(1))) void*)(wp + (k + 1) * 4096 + c * 512 + lane * 8),
            (__attribute__((address_space(3))) void*)(&smB[buf ^ 1][c * 512]), 16, 0, 0);
      }
      // Next-k idx from LDS (conflict-free: 27*lo mod 32 distinct; quad-broadcast).
      #pragma unroll
      for (int rt = 0; rt < 2; ++rt) gi[rt] = sIdx[ioff[rt] + k + 1];
    }
    // B fragments from LDS (shared by all 4 waves).
    const short8* bl = (const short8*)smB[buf];
    short8 b[8];
    #pragma unroll
    for (int t = 0; t < 8; ++t) b[t] = bl[t * 64 + lane];
    // 16 MFMAs.
    #pragma unroll
    for (int s = 0; s < 2; ++s)
      #pragma unroll
      for (int rt = 0; rt < 2; ++rt)
        #pragma unroll
        for (int ct = 0; ct < 4; ++ct)
          acc[rt][ct] = __builtin_amdgcn_mfma_f32_16x16x32_bf16(a[rt][s], b[s * 4 + ct], acc[rt][ct], 0, 0, 0);
    // WAR guard for smB double-buffer (R9 structure: measured service-cap saturation).
    __syncthreads();
  }

  if (MODE == 0) {
    // Epilogue v2: pack the block's 128x64 bf16 tile into LDS (exactly 16 KB = smB),
    // then store as full-128B-line int4 (kills write-allocate/RMW partial-sector traffic).
    ushort* sm = (ushort*)smB;        // [128][64], safe: final loop barrier passed
    #pragma unroll
    for (int rt = 0; rt < 2; ++rt) {
      int br = wid * 32 + rt * 16 + quad * 4;
      #pragma unroll
      for (int ct = 0; ct < 4; ++ct) {
        int col = ct * 16 + lo;
        #pragma unroll
        for (int j = 0; j < 4; ++j) {
          float v = acc[rt][ct][j];
          v = v > 0.0f ? v : 0.0f;
          sm[(br + j) * 64 + col] = f2bf(v);
        }
      }
    }
    __syncthreads();
    // Cooperative coalesced store: 1024 int4 (16 KB), 4 per thread, full lines.
    const int4* sm4 = (const int4*)smB;
    int4* gb = (int4*)(out_bf + (size_t)blockIdx.x * 8192);
    const long limit = (long)n * 64 - (long)blockIdx.x * 8192;  // ushorts remaining
    #pragma unroll
    for (int u = 0; u < 4; ++u) {
      int j4 = tid + 256 * u;
      if ((long)j4 * 8 + 8 <= limit) gb[j4] = sm4[j4];
    }
  } else {
    // fp32 output: 16 lanes x 4B = complete 64B sectors; direct stores are fine.
    #pragma unroll
    for (int rt = 0; rt < 2; ++rt) {
      int rbase = mw + rt * 16 + quad * 4;
      #pragma unroll
      for (int ct = 0; ct < 4; ++ct) {
        int col = ct * 16 + lo;
        #pragma unroll
        for (int j = 0; j < 4; ++j) {
          int r = rbase + j;
          if (r < n) {
            float v = acc[rt][ct][j] + resid[r * 64 + col];
            v = v > 0.0f ? v : 0.0f;
            out_f[r * 64 + col] = v;
          }
        }
      }
    }
  }
}

extern "C" void kernel_launch(void* const* d_in, const int* in_sizes, int n_in,
                              void* d_out, int out_size, void* d_ws, size_t ws_size,
                              hipStream_t stream) {
  const float* x   = (const float*)d_in[0];
  const int*   nbr = (const int*)d_in[1];
  const float* W0  = (const float*)d_in[2];
  const float* W1  = (const float*)d_in[3];
  float* out = (float*)d_out;

  const int n    = NV;
  const int nc   = NV * 64;        // 9,600,000
  const int nc4  = nc / 4;         // 2,400,000
  const int wtot = KOFF * 4096;    // 110,592

  ushort* xb  = (ushort*)d_ws;
  ushort* yb  = xb + nc;
  ushort* wp0 = yb + nc;
  ushort* wp1 = wp0 + wtot;

  const int prep_units = nc4 + 2 * wtot;
  prep_kernel<<<(prep_units + 255) / 256, 256, 0, stream>>>(x, W0, W1, xb, wp0, wp1, nc4, wtot);

  const int grid = (n + 127) / 128;  // 1172 four-wave blocks (entire grid co-resident)
  conv_kernel<0><<<grid, 256, 0, stream>>>(xb, nbr, wp0, nullptr, yb, nullptr, n);
  conv_kernel<1><<<grid, 256, 0, stream>>>(yb, nbr, wp1, x, nullptr, out, n);
}